// Round 9
// baseline (887.835 us; speedup 1.0000x reference)
//
#include <hip/hip_runtime.h>

typedef __attribute__((ext_vector_type(8))) short s16x8;
typedef __attribute__((ext_vector_type(8))) unsigned short u16x8;
typedef __attribute__((ext_vector_type(4))) unsigned short u16x4;
typedef __attribute__((ext_vector_type(4))) float f32x4;

__device__ inline float bf2f(unsigned short h) {
  union { unsigned int u; float f; } x; x.u = ((unsigned int)h) << 16; return x.f;
}
__device__ inline unsigned short f2bf(float f) {
  union { float f; unsigned int u; } x; x.f = f;
  unsigned int u = x.u;
  return (unsigned short)((u + 0x7fffu + ((u >> 16) & 1u)) >> 16);
}

// ---------------------------------------------------------------------------
// f32 -> bf16 cast with output row remap. cols = 1<<shift, multiple of 8.
// ---------------------------------------------------------------------------
__global__ __launch_bounds__(256) void cvt_bf16(const float* __restrict__ in,
                                                unsigned short* __restrict__ out,
                                                long long n, int shift, int ldo) {
  long long i = (long long)blockIdx.x * 256 + threadIdx.x;
  long long stride = (long long)gridDim.x * 256;
  long long nchunks = n >> 3;
  for (; i < nchunks; i += stride) {
    long long e = i << 3;
    long long r = e >> shift;
    int c = (int)(e & ((1LL << shift) - 1));
    const float4* p = (const float4*)(in + e);
    float4 f0 = p[0], f1 = p[1];
    u16x8 u;
    u[0] = f2bf(f0.x); u[1] = f2bf(f0.y); u[2] = f2bf(f0.z); u[3] = f2bf(f0.w);
    u[4] = f2bf(f1.x); u[5] = f2bf(f1.y); u[6] = f2bf(f1.z); u[7] = f2bf(f1.w);
    *(u16x8*)&out[r * (long long)ldo + c] = u;
  }
}

// ---------------------------------------------------------------------------
// flat cast of w1 (n1 elems) and w2 (n2 elems) into adjacent bf16 outputs
// (out = w1_16 base; w2_16 == w1_16 + n1).
// ---------------------------------------------------------------------------
__global__ __launch_bounds__(256) void cvt_weights(const float* __restrict__ w1,
                                                   const float* __restrict__ w2,
                                                   unsigned short* __restrict__ out,
                                                   long long n1, long long ntot) {
  long long i = (long long)blockIdx.x * 256 + threadIdx.x;
  long long stride = (long long)gridDim.x * 256;
  long long nchunks = ntot >> 3;
  for (; i < nchunks; i += stride) {
    long long e = i << 3;
    const float4* p = (e < n1) ? (const float4*)(w1 + e) : (const float4*)(w2 + (e - n1));
    float4 f0 = p[0], f1 = p[1];
    u16x8 u;
    u[0] = f2bf(f0.x); u[1] = f2bf(f0.y); u[2] = f2bf(f0.z); u[3] = f2bf(f0.w);
    u[4] = f2bf(f1.x); u[5] = f2bf(f1.y); u[6] = f2bf(f1.z); u[7] = f2bf(f1.w);
    *(u16x8*)&out[e] = u;
  }
}

// ---------------------------------------------------------------------------
// per-batch fused cast+transpose: in f32 [rows][cols] -> out_n bf16 [rows][cols]
// AND out_t bf16 [cols][rows]. 64x64 tiles, reads f32 input exactly once.
// ---------------------------------------------------------------------------
__global__ __launch_bounds__(256) void cvt_transpose(const float* __restrict__ in,
                                                     unsigned short* __restrict__ out_n,
                                                     unsigned short* __restrict__ out_t,
                                                     int rows, int cols) {
  __shared__ unsigned short tile[64][72];
  long long zoff = (long long)blockIdx.z * rows * cols;
  const float* src = in + zoff;
  unsigned short* dstn = out_n + zoff;
  unsigned short* dstt = out_t + zoff;
  int k0 = blockIdx.x * 64, d0 = blockIdx.y * 64;
  int t = threadIdx.x;
  int rr = t >> 4;
  int cc = (t & 15) * 4;
#pragma unroll
  for (int i = 0; i < 4; ++i) {
    int k = rr + i * 16;
    float4 v = *(const float4*)&src[(long long)(k0 + k) * cols + d0 + cc];
    u16x4 u;
    u[0] = f2bf(v.x); u[1] = f2bf(v.y); u[2] = f2bf(v.z); u[3] = f2bf(v.w);
    *(u16x4*)&dstn[(long long)(k0 + k) * cols + d0 + cc] = u;
    *(u16x4*)&tile[k][cc] = u;
  }
  __syncthreads();
#pragma unroll
  for (int i = 0; i < 4; ++i) {
    int d = rr + i * 16;
    u16x4 v;
#pragma unroll
    for (int j = 0; j < 4; ++j) v[j] = tile[cc + j][d];
    *(u16x4*)&dstt[(long long)(d0 + d) * rows + k0 + cc] = v;
  }
}

// ---------------------------------------------------------------------------
// 256x256 bf16 GEMM, B^T layout, persistent-block tile loop.
// SINGLE instantiation; epilogue behavior selected by runtime `flags`
// (uniform branches, epilogue-only — K-loop codegen identical for all
// call sites; avoids template-instantiation codegen cross-perturbation):
//   bit0 OUT_BF16   : store bf16 (else f32)
//   bit1 HAS_BIAS   : add bias[col], multiply by scale
//   bit2 EXP_SM     : store exp(acc); atomic per-row sums into part[]
//   bit3 ROWSCALE   : multiply rows by 1/part[row]
// Per tile: 8-phase K-loop (BK=64, dbuf, counted vmcnt(6), setprio,
// XOR-swizzled LDS); next tile's prologue issued before the epilogue.
// Requires: M%256==0, N%256==0, K%128==0, ntiles%gridDim.x==0, grid%8==0.
// ---------------------------------------------------------------------------
__global__ __launch_bounds__(512, 1) void gemm256(
    const unsigned short* __restrict__ A, const unsigned short* __restrict__ Bt,
    void* __restrict__ C, const float* __restrict__ bias,
    int K, int lda, int ldb, int ldc,
    long long sA, long long sB, long long sC, float scale,
    int gx, int gy, int ntiles, float* __restrict__ part, int flags) {
  __shared__ char lds[131072];
  const int t = threadIdx.x;
  const int l = t & 63, w = t >> 6;
  const int wm = w >> 2, wn = w & 3;

  const int nwg = gridDim.x;
  const int id = blockIdx.x;
  const int sid = (id & 7) * (nwg >> 3) + (id >> 3);

  const int trow = t >> 2;
  const int kl8 = ((t & 3) ^ ((t >> 3) & 3)) * 8;
  const int Lt = t * 16;
  const int lo = (l & 15) * 64 + ((((l >> 4) ^ (((l & 15) >> 1) & 3))) << 4);
  const int nt = K >> 6;
  const int cl = l & 15, rg = (l >> 4) * 4;
  const f32x4 zero4 = {0.f, 0.f, 0.f, 0.f};

  f32x4 acc[8][4];

#define GLOAD(SRC, DST)                                                              \
  __builtin_amdgcn_global_load_lds(                                                  \
      (const __attribute__((address_space(1))) void*)(SRC),                          \
      (__attribute__((address_space(3))) void*)(DST), 16, 0, 0)
#define STAGE_A(GP, KT, KSL)                                                         \
  {                                                                                  \
    char* d_ = lds + (((KT) & 1) * 65536) + ((KSL) * 16384);                         \
    const unsigned short* g_ = (GP) + (long long)(KT) * 64 + (KSL) * 32;             \
    GLOAD(g_, d_ + Lt);                                                              \
    GLOAD(g_ + 128 * lda, d_ + 8192 + Lt);                                           \
  }
#define STAGE_B(GP, KT, KSL)                                                         \
  {                                                                                  \
    char* d_ = lds + (((KT) & 1) * 65536) + 32768 + ((KSL) * 16384);                 \
    const unsigned short* g_ = (GP) + (long long)(KT) * 64 + (KSL) * 32;             \
    GLOAD(g_, d_ + Lt);                                                              \
    GLOAD(g_ + 128 * ldb, d_ + 8192 + Lt);                                           \
  }
#define PROLOG(GA, GB)                                                               \
  {                                                                                  \
    STAGE_A(GA, 0, 0); STAGE_A(GA, 0, 1); STAGE_B(GB, 0, 0); STAGE_B(GB, 0, 1);      \
    STAGE_B(GB, 1, 0); STAGE_A(GA, 1, 0); STAGE_B(GB, 1, 1);                         \
  }
#define READ_A(MH, KSL, CB)                                                          \
  _Pragma("unroll")                                                                  \
  for (int m_ = 0; m_ < 4; ++m_)                                                     \
    af[m_] = *(const s16x8*)((CB) + (KSL) * 16384 + wm * 8192 + ((MH) * 4 + m_) * 1024 + lo);
#define READ_B(KSL, CB)                                                              \
  _Pragma("unroll")                                                                  \
  for (int n_ = 0; n_ < 4; ++n_)                                                     \
    bf[n_] = *(const s16x8*)((CB) + 32768 + (KSL) * 16384 + wn * 4096 + n_ * 1024 + lo);
#define MFMA_Q(MH)                                                                   \
  __builtin_amdgcn_s_setprio(1);                                                     \
  _Pragma("unroll")                                                                  \
  for (int m_ = 0; m_ < 4; ++m_)                                                     \
    _Pragma("unroll")                                                                \
    for (int n_ = 0; n_ < 4; ++n_)                                                   \
      acc[(MH) * 4 + m_][n_] =                                                       \
          __builtin_amdgcn_mfma_f32_16x16x32_bf16(af[m_], bf[n_], acc[(MH) * 4 + m_][n_], 0, 0, 0); \
  __builtin_amdgcn_s_setprio(0);
#define BAR __builtin_amdgcn_s_barrier()
#define LGKM0 asm volatile("s_waitcnt lgkmcnt(0)" ::: "memory")

  // first tile bases + prologue
  long long m0, n0;
  int bz;
  const unsigned short *gA, *gB;
  {
    const int tile = sid;
    const int bx = tile % gx;
    const int rem = tile / gx;
    const int by = rem % gy;
    bz = rem / gy;
    m0 = (long long)by * 256;
    n0 = (long long)bx * 256;
    gA = A + bz * sA + (m0 + trow) * lda + kl8;
    gB = Bt + bz * sB + (n0 + trow) * ldb + kl8;
  }
  PROLOG(gA, gB);

  for (int tile = sid; tile < ntiles; tile += nwg) {
    asm volatile("s_waitcnt vmcnt(6)" ::: "memory");
    BAR;
#pragma unroll
    for (int m = 0; m < 8; ++m)
#pragma unroll
      for (int n = 0; n < 4; ++n) acc[m][n] = zero4;

    s16x8 af[4], bf[4];
    for (int kt = 0; kt < nt; ++kt) {
      const char* cb = lds + (kt & 1) * 65536;
      const bool p1 = (kt + 1 < nt), p2 = (kt + 2 < nt);
      READ_B(0, cb); READ_A(0, 0, cb);
      if (p1) STAGE_A(gA, kt + 1, 1);
      BAR; LGKM0; MFMA_Q(0); BAR;
      READ_A(1, 0, cb);
      if (p2) STAGE_B(gB, kt + 2, 0);
      BAR; LGKM0; MFMA_Q(1); BAR;
      READ_B(1, cb); READ_A(0, 1, cb);
      if (p2) STAGE_A(gA, kt + 2, 0);
      BAR; LGKM0; MFMA_Q(0); BAR;
      READ_A(1, 1, cb);
      if (p2) STAGE_B(gB, kt + 2, 1);
      BAR; LGKM0; MFMA_Q(1);
      if (p2)      asm volatile("s_waitcnt vmcnt(6)" ::: "memory");
      else         asm volatile("s_waitcnt vmcnt(0)" ::: "memory");
      BAR;
    }
    // All LDS reads of this tile are closed; issue NEXT tile's prologue now
    // so the HBM fill flies under the epilogue below.
    const bool more = (tile + nwg) < ntiles;
    long long m0n = 0, n0n = 0;
    int bzn = 0;
    const unsigned short *gAn = gA, *gBn = gB;
    if (more) {
      const int tl = tile + nwg;
      const int bx = tl % gx;
      const int rem = tl / gx;
      const int by = rem % gy;
      bzn = rem / gy;
      m0n = (long long)by * 256;
      n0n = (long long)bx * 256;
      gAn = A + bzn * sA + (m0n + trow) * lda + kl8;
      gBn = Bt + bzn * sB + (n0n + trow) * ldb + kl8;
      PROLOG(gAn, gBn);
    }

    // ---- epilogue for current tile (runtime-flag dispatch, uniform) ----
    if (flags & 4) {
#pragma unroll
      for (int m = 0; m < 8; ++m) {
#pragma unroll
        for (int j = 0; j < 4; ++j) {
          float s = 0.f;
#pragma unroll
          for (int n = 0; n < 4; ++n) {
            float e = __expf(acc[m][n][j]);
            acc[m][n][j] = e;
            s += e;
          }
          s += __shfl_xor(s, 1); s += __shfl_xor(s, 2);
          s += __shfl_xor(s, 4); s += __shfl_xor(s, 8);
          if (cl == 0)
            atomicAdd(&part[(long long)bz * 2048 + m0 + wm * 128 + m * 16 + rg + j], s);
        }
      }
    }
#pragma unroll
    for (int m = 0; m < 8; ++m) {
      long long row = m0 + wm * 128 + m * 16 + rg;
      float rv[4];
      if (flags & 8) {
#pragma unroll
        for (int j = 0; j < 4; ++j)
          rv[j] = 1.0f / part[(long long)bz * 2048 + row + j];
      }
#pragma unroll
      for (int n = 0; n < 4; ++n) {
        long long col = n0 + wn * 64 + n * 16 + cl;
        float bb = (flags & 2) ? bias[col] : 0.0f;
#pragma unroll
        for (int j = 0; j < 4; ++j) {
          float v = (flags & 4) ? acc[m][n][j] : (acc[m][n][j] + bb) * scale;
          if (flags & 8) v *= rv[j];
          if (flags & 1)
            ((unsigned short*)C)[bz * sC + (row + j) * ldc + col] = f2bf(v);
          else
            ((float*)C)[bz * sC + (row + j) * ldc + col] = v;
        }
      }
    }

    asm volatile("s_waitcnt vmcnt(0)" ::: "memory");
    BAR;
    if (more) { m0 = m0n; n0 = n0n; bz = bzn; gA = gAn; gB = gBn; }
  }
#undef GLOAD
#undef STAGE_A
#undef STAGE_B
#undef PROLOG
#undef READ_A
#undef READ_B
#undef MFMA_Q
#undef BAR
#undef LGKM0
}

// ---------------------------------------------------------------------------
// Host launcher. ws layout (bytes):
//   fused  [32768][2048] bf16 : 0          .. 134217728   (bert | attn_out)
//   bfq    [32768][1024] bf16 : 134217728  .. 201326592
//   know16 [16][2048][1024]   : 201326592  .. 268435456
//   knowT  [16][1024][2048]   : 268435456  .. 335544320
//   w1_16  [1024][1024]       : 335544320  .. 337641472
//   w2_16  [1024][2048]       : 337641472  .. 341835776
//   part   [32768] f32        : 341835776  .. 341966848
// E = exp(scores) lives in d_out (bf16), then d_out is overwritten by the
// final fusion GEMM (f32). Softmax normalization is folded into GEMM4
// (reads part[] directly, reciprocal inline).
// ---------------------------------------------------------------------------
extern "C" void kernel_launch(void* const* d_in, const int* in_sizes, int n_in,
                              void* d_out, int out_size, void* d_ws, size_t ws_size,
                              hipStream_t stream) {
  const float* bert = (const float*)d_in[0];
  const float* know = (const float*)d_in[1];
  const float* w1w  = (const float*)d_in[2];
  const float* w1b  = (const float*)d_in[3];
  const float* w2w  = (const float*)d_in[4];
  const float* w2b  = (const float*)d_in[5];

  char* ws = (char*)d_ws;
  unsigned short* fused  = (unsigned short*)(ws);
  unsigned short* bfq    = (unsigned short*)(ws + 134217728LL);
  unsigned short* know16 = (unsigned short*)(ws + 201326592LL);
  unsigned short* knowT  = (unsigned short*)(ws + 268435456LL);
  unsigned short* w1_16  = (unsigned short*)(ws + 335544320LL);
  float*          part   = (float*)(ws + 341835776LL);
  unsigned short* P      = (unsigned short*)d_out;

  // casts + fused know cast/transpose; zero the atomic row-sum buffer
  hipMemsetAsync(part, 0, 32768 * sizeof(float), stream);
  cvt_bf16<<<2048, 256, 0, stream>>>(bert, fused, 33554432LL, 10, 2048);
  cvt_weights<<<768, 256, 0, stream>>>(w1w, w2w, w1_16, 1048576LL, 3145728LL);
  cvt_transpose<<<dim3(32, 16, 16), 256, 0, stream>>>(know, know16, knowT, 2048, 1024);

  // 1) bfq = (bert @ w1^T + b1) / 32          M=32768 N=1024 K=1024, 512 tiles
  gemm256<<<256, 512, 0, stream>>>(
      fused, w1_16, bfq, w1b, 1024, 2048, 1024, 1024, 0, 0, 0, 0.03125f,
      4, 128, 512, nullptr, /*flags=*/1 | 2);

  // 2) E = exp(bfq @ know^T) + atomic row sums    M=2048 N=2048 K=1024, 1024 tiles
  gemm256<<<256, 512, 0, stream>>>(
      bfq, know16, P, nullptr, 1024, 1024, 1024, 2048,
      2048LL * 1024, 2048LL * 1024, 2048LL * 2048, 1.0f,
      8, 8, 1024, part, /*flags=*/1 | 4);

  // 3) attn_out = (E @ know) / rowsum         M=2048 N=1024 K=2048, 512 tiles
  gemm256<<<256, 512, 0, stream>>>(
      P, knowT, fused + 1024, nullptr, 2048, 2048, 2048, 2048,
      2048LL * 2048, 1024LL * 2048, 2048LL * 2048, 1.0f,
      4, 8, 512, part, /*flags=*/1 | 8);

  // 4) out = fused @ w2^T + b2  (f32)         M=32768 N=1024 K=2048, 512 tiles
  gemm256<<<256, 512, 0, stream>>>(
      fused, w1_16 + 1048576, d_out, w2b, 2048, 2048, 2048, 1024, 0, 0, 0, 1.0f,
      4, 128, 512, nullptr, /*flags=*/2);
}

// Round 10
// 622.668 us; speedup vs baseline: 1.4259x; 1.4259x over previous
//
#include <hip/hip_runtime.h>

typedef __attribute__((ext_vector_type(8))) short s16x8;
typedef __attribute__((ext_vector_type(8))) unsigned short u16x8;
typedef __attribute__((ext_vector_type(4))) unsigned short u16x4;
typedef __attribute__((ext_vector_type(4))) float f32x4;

__device__ inline float bf2f(unsigned short h) {
  union { unsigned int u; float f; } x; x.u = ((unsigned int)h) << 16; return x.f;
}
__device__ inline unsigned short f2bf(float f) {
  union { float f; unsigned int u; } x; x.f = f;
  unsigned int u = x.u;
  return (unsigned short)((u + 0x7fffu + ((u >> 16) & 1u)) >> 16);
}

// ---------------------------------------------------------------------------
// f32 -> bf16 cast with output row remap. cols = 1<<shift, multiple of 8.
// ---------------------------------------------------------------------------
__global__ __launch_bounds__(256) void cvt_bf16(const float* __restrict__ in,
                                                unsigned short* __restrict__ out,
                                                long long n, int shift, int ldo) {
  long long i = (long long)blockIdx.x * 256 + threadIdx.x;
  long long stride = (long long)gridDim.x * 256;
  long long nchunks = n >> 3;
  for (; i < nchunks; i += stride) {
    long long e = i << 3;
    long long r = e >> shift;
    int c = (int)(e & ((1LL << shift) - 1));
    const float4* p = (const float4*)(in + e);
    float4 f0 = p[0], f1 = p[1];
    u16x8 u;
    u[0] = f2bf(f0.x); u[1] = f2bf(f0.y); u[2] = f2bf(f0.z); u[3] = f2bf(f0.w);
    u[4] = f2bf(f1.x); u[5] = f2bf(f1.y); u[6] = f2bf(f1.z); u[7] = f2bf(f1.w);
    *(u16x8*)&out[r * (long long)ldo + c] = u;
  }
}

// ---------------------------------------------------------------------------
// flat cast of w1 (n1 elems) then w2 into adjacent bf16 outputs
// (out = w1_16 base; w2_16 == w1_16 + n1).
// ---------------------------------------------------------------------------
__global__ __launch_bounds__(256) void cvt_weights(const float* __restrict__ w1,
                                                   const float* __restrict__ w2,
                                                   unsigned short* __restrict__ out,
                                                   long long n1, long long ntot) {
  long long i = (long long)blockIdx.x * 256 + threadIdx.x;
  long long stride = (long long)gridDim.x * 256;
  long long nchunks = ntot >> 3;
  for (; i < nchunks; i += stride) {
    long long e = i << 3;
    const float4* p = (e < n1) ? (const float4*)(w1 + e) : (const float4*)(w2 + (e - n1));
    float4 f0 = p[0], f1 = p[1];
    u16x8 u;
    u[0] = f2bf(f0.x); u[1] = f2bf(f0.y); u[2] = f2bf(f0.z); u[3] = f2bf(f0.w);
    u[4] = f2bf(f1.x); u[5] = f2bf(f1.y); u[6] = f2bf(f1.z); u[7] = f2bf(f1.w);
    *(u16x8*)&out[e] = u;
  }
}

// ---------------------------------------------------------------------------
// per-batch fused cast+transpose: in f32 [rows][cols] -> out_n bf16 [rows][cols]
// AND out_t bf16 [cols][rows]. 64x64 tiles, reads f32 input exactly once.
// ---------------------------------------------------------------------------
__global__ __launch_bounds__(256) void cvt_transpose(const float* __restrict__ in,
                                                     unsigned short* __restrict__ out_n,
                                                     unsigned short* __restrict__ out_t,
                                                     int rows, int cols) {
  __shared__ unsigned short tile[64][72];
  long long zoff = (long long)blockIdx.z * rows * cols;
  const float* src = in + zoff;
  unsigned short* dstn = out_n + zoff;
  unsigned short* dstt = out_t + zoff;
  int k0 = blockIdx.x * 64, d0 = blockIdx.y * 64;
  int t = threadIdx.x;
  int rr = t >> 4;
  int cc = (t & 15) * 4;
#pragma unroll
  for (int i = 0; i < 4; ++i) {
    int k = rr + i * 16;
    float4 v = *(const float4*)&src[(long long)(k0 + k) * cols + d0 + cc];
    u16x4 u;
    u[0] = f2bf(v.x); u[1] = f2bf(v.y); u[2] = f2bf(v.z); u[3] = f2bf(v.w);
    *(u16x4*)&dstn[(long long)(k0 + k) * cols + d0 + cc] = u;
    *(u16x4*)&tile[k][cc] = u;
  }
  __syncthreads();
#pragma unroll
  for (int i = 0; i < 4; ++i) {
    int d = rr + i * 16;
    u16x4 v;
#pragma unroll
    for (int j = 0; j < 4; ++j) v[j] = tile[cc + j][d];
    *(u16x4*)&dstt[(long long)(d0 + d) * rows + k0 + cc] = v;
  }
}

// ---------------------------------------------------------------------------
// rinv[i] = 1 / sum_{b<8} part[i*8+b]
// ---------------------------------------------------------------------------
__global__ __launch_bounds__(256) void rowsum_inv(const float* __restrict__ part,
                                                  float* __restrict__ rinv, int nrows) {
  int i = blockIdx.x * 256 + threadIdx.x;
  if (i < nrows) {
    const float* p = part + (long long)i * 8;
    float s = 0.f;
#pragma unroll
    for (int k = 0; k < 8; ++k) s += p[k];
    rinv[i] = 1.0f / s;
  }
}

// ---------------------------------------------------------------------------
// 256x256 bf16 GEMM, B^T layout (8-phase schedule; R6-identical).
// EXP_SM epilogue: write exp(acc) and per-row partial sums to `part`
// (assumes gx==8, HAS_BIAS=false, scale=1). ROWSCALE epilogue: multiply
// output rows by rinv[bz*2048+row].
// ---------------------------------------------------------------------------
template <bool OUT_BF16, bool HAS_BIAS, bool EXP_SM, bool ROWSCALE>
__global__ __launch_bounds__(512, 1) void gemm256(
    const unsigned short* __restrict__ A, const unsigned short* __restrict__ Bt,
    void* __restrict__ C, const float* __restrict__ bias,
    int K, int lda, int ldb, int ldc,
    long long sA, long long sB, long long sC, float scale,
    int gx, int gy, float* __restrict__ part, const float* __restrict__ rinv) {
  __shared__ char lds[131072];
  const int t = threadIdx.x;
  const int l = t & 63, w = t >> 6;
  const int wm = w >> 2, wn = w & 3;

  const int nwg = gridDim.x;
  const int id = blockIdx.x;
  const int sid = (id & 7) * (nwg >> 3) + (id >> 3);
  const int bx = sid % gx;
  const int rem = sid / gx;
  const int by = rem % gy;
  const int bz = rem / gy;

  A += (long long)bz * sA;
  Bt += (long long)bz * sB;
  const long long m0 = (long long)by * 256;
  const long long n0 = (long long)bx * 256;

  const int trow = t >> 2;
  const int kl8 = ((t & 3) ^ ((t >> 3) & 3)) * 8;
  const unsigned short* gA = A + (m0 + trow) * lda + kl8;
  const unsigned short* gB = Bt + (n0 + trow) * ldb + kl8;
  const int Lt = t * 16;

  const int lo = (l & 15) * 64 + ((((l >> 4) ^ (((l & 15) >> 1) & 3))) << 4);

  f32x4 acc[8][4] = {};
  const int nt = K >> 6;

#define STAGE_A(KT, KSL)                                                             \
  {                                                                                  \
    char* d_ = lds + (((KT) & 1) * 65536) + ((KSL) * 16384);                         \
    const unsigned short* g_ = gA + (long long)(KT) * 64 + (KSL) * 32;               \
    __builtin_amdgcn_global_load_lds(                                                \
        (const __attribute__((address_space(1))) void*)g_,                           \
        (__attribute__((address_space(3))) void*)(d_ + Lt), 16, 0, 0);               \
    __builtin_amdgcn_global_load_lds(                                                \
        (const __attribute__((address_space(1))) void*)(g_ + 128 * lda),             \
        (__attribute__((address_space(3))) void*)(d_ + 8192 + Lt), 16, 0, 0);        \
  }
#define STAGE_B(KT, KSL)                                                             \
  {                                                                                  \
    char* d_ = lds + (((KT) & 1) * 65536) + 32768 + ((KSL) * 16384);                 \
    const unsigned short* g_ = gB + (long long)(KT) * 64 + (KSL) * 32;               \
    __builtin_amdgcn_global_load_lds(                                                \
        (const __attribute__((address_space(1))) void*)g_,                           \
        (__attribute__((address_space(3))) void*)(d_ + Lt), 16, 0, 0);               \
    __builtin_amdgcn_global_load_lds(                                                \
        (const __attribute__((address_space(1))) void*)(g_ + 128 * ldb),             \
        (__attribute__((address_space(3))) void*)(d_ + 8192 + Lt), 16, 0, 0);        \
  }

  STAGE_A(0, 0); STAGE_A(0, 1); STAGE_B(0, 0); STAGE_B(0, 1);
  STAGE_B(1, 0); STAGE_A(1, 0); STAGE_B(1, 1);
  asm volatile("s_waitcnt vmcnt(6)" ::: "memory");
  __builtin_amdgcn_s_barrier();

  s16x8 af[4], bf[4];

#define READ_A(MH, KSL, CB)                                                          \
  _Pragma("unroll")                                                                  \
  for (int m_ = 0; m_ < 4; ++m_)                                                     \
    af[m_] = *(const s16x8*)((CB) + (KSL) * 16384 + wm * 8192 + ((MH) * 4 + m_) * 1024 + lo);
#define READ_B(KSL, CB)                                                              \
  _Pragma("unroll")                                                                  \
  for (int n_ = 0; n_ < 4; ++n_)                                                     \
    bf[n_] = *(const s16x8*)((CB) + 32768 + (KSL) * 16384 + wn * 4096 + n_ * 1024 + lo);
#define MFMA_Q(MH)                                                                   \
  __builtin_amdgcn_s_setprio(1);                                                     \
  _Pragma("unroll")                                                                  \
  for (int m_ = 0; m_ < 4; ++m_)                                                     \
    _Pragma("unroll")                                                                \
    for (int n_ = 0; n_ < 4; ++n_)                                                   \
      acc[(MH) * 4 + m_][n_] =                                                       \
          __builtin_amdgcn_mfma_f32_16x16x32_bf16(af[m_], bf[n_], acc[(MH) * 4 + m_][n_], 0, 0, 0); \
  __builtin_amdgcn_s_setprio(0);
#define BAR __builtin_amdgcn_s_barrier()
#define LGKM0 asm volatile("s_waitcnt lgkmcnt(0)" ::: "memory")

  for (int kt = 0; kt < nt; ++kt) {
    const char* cb = lds + (kt & 1) * 65536;
    const bool p1 = (kt + 1 < nt), p2 = (kt + 2 < nt);
    READ_B(0, cb); READ_A(0, 0, cb);
    if (p1) STAGE_A(kt + 1, 1);
    BAR; LGKM0; MFMA_Q(0); BAR;
    READ_A(1, 0, cb);
    if (p2) STAGE_B(kt + 2, 0);
    BAR; LGKM0; MFMA_Q(1); BAR;
    READ_B(1, cb); READ_A(0, 1, cb);
    if (p2) STAGE_A(kt + 2, 0);
    BAR; LGKM0; MFMA_Q(0); BAR;
    READ_A(1, 1, cb);
    if (p2) STAGE_B(kt + 2, 1);
    BAR; LGKM0; MFMA_Q(1);
    if (p2)      asm volatile("s_waitcnt vmcnt(6)" ::: "memory");
    else         asm volatile("s_waitcnt vmcnt(0)" ::: "memory");
    BAR;
  }
#undef STAGE_A
#undef STAGE_B
#undef READ_A
#undef READ_B
#undef MFMA_Q
#undef BAR
#undef LGKM0

  const int cl = l & 15, rg = (l >> 4) * 4;

  if (EXP_SM) {
    float* pl = (float*)lds;
#pragma unroll
    for (int m = 0; m < 8; ++m) {
#pragma unroll
      for (int j = 0; j < 4; ++j) {
        float s = 0.f;
#pragma unroll
        for (int n = 0; n < 4; ++n) {
          float e = __expf(acc[m][n][j]);
          acc[m][n][j] = e;
          s += e;
        }
        s += __shfl_xor(s, 1); s += __shfl_xor(s, 2);
        s += __shfl_xor(s, 4); s += __shfl_xor(s, 8);
        if (cl == 0) pl[wn * 256 + wm * 128 + m * 16 + rg + j] = s;
      }
    }
    __syncthreads();
    if (t < 256) {
      float s = pl[t] + pl[256 + t] + pl[512 + t] + pl[768 + t];
      part[((long long)bz * 2048 + m0 + t) * 8 + bx] = s;
    }
  }

#pragma unroll
  for (int m = 0; m < 8; ++m) {
    long long row = m0 + wm * 128 + m * 16 + rg;
    float rv[4];
    if (ROWSCALE) {
#pragma unroll
      for (int j = 0; j < 4; ++j) rv[j] = rinv[(long long)bz * 2048 + row + j];
    }
#pragma unroll
    for (int n = 0; n < 4; ++n) {
      long long col = n0 + wn * 64 + n * 16 + cl;
      float bb = HAS_BIAS ? bias[col] : 0.0f;
#pragma unroll
      for (int j = 0; j < 4; ++j) {
        float v = EXP_SM ? acc[m][n][j] : (acc[m][n][j] + bb) * scale;
        if (ROWSCALE) v *= rv[j];
        if (OUT_BF16)
          ((unsigned short*)C)[bz * sC + (row + j) * ldc + col] = f2bf(v);
        else
          ((float*)C)[bz * sC + (row + j) * ldc + col] = v;
      }
    }
  }
}

// ---------------------------------------------------------------------------
// Host launcher. ws layout (bytes):
//   fused  [32768][2048] bf16 : 0          .. 134217728   (bert | attn_out)
//   bfq    [32768][1024] bf16 : 134217728  .. 201326592
//   know16 [16][2048][1024]   : 201326592  .. 268435456
//   knowT  [16][1024][2048]   : 268435456  .. 335544320
//   w1_16  [1024][1024]       : 335544320  .. 337641472
//   w2_16  [1024][2048]       : 337641472  .. 341835776   (= w1_16 + 1M elems)
//   part   [32768][8] f32     : 341835776  .. 342884352
//   rinv   [32768] f32        : 342884352  .. 343015424
// E = exp(scores) lives in d_out (bf16), then d_out is overwritten by the
// final fusion GEMM (f32). Softmax normalization is folded into GEMM4's
// output rows (row-constant factor commutes with the PV reduction).
// ---------------------------------------------------------------------------
extern "C" void kernel_launch(void* const* d_in, const int* in_sizes, int n_in,
                              void* d_out, int out_size, void* d_ws, size_t ws_size,
                              hipStream_t stream) {
  const float* bert = (const float*)d_in[0];
  const float* know = (const float*)d_in[1];
  const float* w1w  = (const float*)d_in[2];
  const float* w1b  = (const float*)d_in[3];
  const float* w2w  = (const float*)d_in[4];
  const float* w2b  = (const float*)d_in[5];

  char* ws = (char*)d_ws;
  unsigned short* fused  = (unsigned short*)(ws);
  unsigned short* bfq    = (unsigned short*)(ws + 134217728LL);
  unsigned short* know16 = (unsigned short*)(ws + 201326592LL);
  unsigned short* knowT  = (unsigned short*)(ws + 268435456LL);
  unsigned short* w1_16  = (unsigned short*)(ws + 335544320LL);
  unsigned short* w2_16  = (unsigned short*)(ws + 337641472LL);
  float*          part   = (float*)(ws + 341835776LL);
  float*          rinv   = (float*)(ws + 342884352LL);
  unsigned short* P      = (unsigned short*)d_out;

  // casts + fused know cast/transpose
  cvt_bf16<<<2048, 256, 0, stream>>>(bert, fused, 33554432LL, 10, 2048);
  cvt_weights<<<768, 256, 0, stream>>>(w1w, w2w, w1_16, 1048576LL, 3145728LL);
  cvt_transpose<<<dim3(32, 16, 16), 256, 0, stream>>>(know, know16, knowT, 2048, 1024);

  // 1) bfq = (bert @ w1^T + b1) / 32          M=32768 N=1024 K=1024
  gemm256<true, true, false, false><<<4 * 128, 512, 0, stream>>>(
      fused, w1_16, bfq, w1b, 1024, 2048, 1024, 1024, 0, 0, 0, 0.03125f, 4, 128,
      nullptr, nullptr);

  // 2) E = exp(bfq @ know^T) + row partial sums   M=2048 N=2048 K=1024
  gemm256<true, false, true, false><<<8 * 8 * 16, 512, 0, stream>>>(
      bfq, know16, P, nullptr, 1024, 1024, 1024, 2048,
      2048LL * 1024, 2048LL * 1024, 2048LL * 2048, 1.0f, 8, 8,
      part, nullptr);

  // 3) rinv = 1/rowsum
  rowsum_inv<<<128, 256, 0, stream>>>(part, rinv, 32768);

  // 4) attn_out = (E @ know) * rinv[row]      M=2048 N=1024 K=2048
  gemm256<true, false, false, true><<<4 * 8 * 16, 512, 0, stream>>>(
      P, knowT, fused + 1024, nullptr, 2048, 2048, 2048, 2048,
      2048LL * 2048, 1024LL * 2048, 2048LL * 2048, 1.0f, 4, 8,
      nullptr, rinv);

  // 5) out = fused @ w2^T + b2  (f32)         M=32768 N=1024 K=2048
  gemm256<false, true, false, false><<<4 * 128, 512, 0, stream>>>(
      fused, w2_16, d_out, w2b, 2048, 2048, 2048, 1024, 0, 0, 0, 1.0f, 4, 128,
      nullptr, nullptr);
}